// Round 8
// baseline (692.659 us; speedup 1.0000x reference)
//
#include <hip/hip_runtime.h>
#include <math.h>
#include <stdint.h>

#define BATCH 64
#define N 128
#define DIM 64
#define ARR_CAP 640
#define AUCTION_ROUNDS 26

typedef unsigned uint32x2_t __attribute__((ext_vector_type(2)));

// branchless monotone float->uint (order-preserving incl. +-inf)
__device__ __forceinline__ unsigned monokey(float x) {
    unsigned b = __float_as_uint(x);
    return b ^ (unsigned)(((int)b >> 31) | (int)0x80000000u);
}
__device__ __forceinline__ float monoval(unsigned k) {
    unsigned b = (k & 0x80000000u) ? (k & 0x7FFFFFFFu) : ~k;
    return __uint_as_float(b);
}

__device__ __forceinline__ unsigned umin_(unsigned a, unsigned b) { return a < b ? a : b; }
__device__ __forceinline__ unsigned umax_(unsigned a, unsigned b) { return a > b ? a : b; }
__device__ __forceinline__ int rfl(int v) { return __builtin_amdgcn_readfirstlane(v); }
__device__ __forceinline__ int rl_i(int v, int l) { return __builtin_amdgcn_readlane(v, l); }
__device__ __forceinline__ float rl_f(float v, int l) {
    return __int_as_float(__builtin_amdgcn_readlane(__float_as_int(v), l));
}

#define DPP_ROR(x, n) __builtin_amdgcn_update_dpp((int)(x), (int)(x), 0x120 + (n), 0xF, 0xF, false)

// full-wave min of packed keys; every lane gets the result. VALU-only.
__device__ __forceinline__ unsigned wave_kmin(unsigned k) {
    unsigned a = (unsigned)DPP_ROR(k, 1);
    unsigned b = (unsigned)DPP_ROR(k, 2);
    k = umin_(k, umin_(a, b));            // 0..2
    a = (unsigned)DPP_ROR(k, 3);
    b = (unsigned)DPP_ROR(k, 6);
    k = umin_(k, umin_(a, b));            // 0..8
    a = (unsigned)DPP_ROR(k, 9);
    k = umin_(k, a);                      // 0..15 (wrap overlap OK for min)
#if __has_builtin(__builtin_amdgcn_permlane16_swap)
    { uint32x2_t r = __builtin_amdgcn_permlane16_swap(k, k, false, false); k = umin_(r[0], r[1]); }
#else
    k = umin_(k, (unsigned)__shfl_xor((int)k, 16));
#endif
#if __has_builtin(__builtin_amdgcn_permlane32_swap)
    { uint32x2_t r = __builtin_amdgcn_permlane32_swap(k, k, false, false); k = umin_(r[0], r[1]); }
#else
    k = umin_(k, (unsigned)__shfl_xor((int)k, 32));
#endif
    return k;
}

// two smallest keys across the wave (disjoint-window rotate-reduce). ks<=kb kept.
__device__ __forceinline__ void wave_kmin2(unsigned& ks, unsigned& kb, int lane) {
    unsigned ps, pb;
#define KM2_COMBINE { unsigned ns = umin_(ks, ps); kb = umin_(umin_(kb, pb), umax_(ks, ps)); ks = ns; }
    ps = (unsigned)DPP_ROR(ks, 1); pb = (unsigned)DPP_ROR(kb, 1); KM2_COMBINE;
    ps = (unsigned)DPP_ROR(ks, 2); pb = (unsigned)DPP_ROR(kb, 2); KM2_COMBINE;
    ps = (unsigned)DPP_ROR(ks, 4); pb = (unsigned)DPP_ROR(kb, 4); KM2_COMBINE;
    ps = (unsigned)DPP_ROR(ks, 8); pb = (unsigned)DPP_ROR(kb, 8); KM2_COMBINE;
#if __has_builtin(__builtin_amdgcn_permlane16_swap)
    {
        uint32x2_t rs = __builtin_amdgcn_permlane16_swap(ks, ks, false, false);
        uint32x2_t rb = __builtin_amdgcn_permlane16_swap(kb, kb, false, false);
        ps = (lane & 16) ? rs[0] : rs[1]; pb = (lane & 16) ? rb[0] : rb[1];
    }
    KM2_COMBINE;
#else
    ps = (unsigned)__shfl_xor((int)ks, 16); pb = (unsigned)__shfl_xor((int)kb, 16); KM2_COMBINE;
#endif
#if __has_builtin(__builtin_amdgcn_permlane32_swap)
    {
        uint32x2_t rs = __builtin_amdgcn_permlane32_swap(ks, ks, false, false);
        uint32x2_t rb = __builtin_amdgcn_permlane32_swap(kb, kb, false, false);
        ps = (lane & 32) ? rs[0] : rs[1]; pb = (lane & 32) ? rb[0] : rb[1];
    }
    KM2_COMBINE;
#else
    ps = (unsigned)__shfl_xor((int)ks, 32); pb = (unsigned)__shfl_xor((int)kb, 32); KM2_COMBINE;
#endif
#undef KM2_COMBINE
}

// One block = one batch, 64 threads (1 wave). Lane owns 1-based columns ja=lane+1, jb=lane+65.
// Capped Jacobi auction warms up column duals v; exact JV (greedy + ARR + Dijkstra) finishes.
__global__ __launch_bounds__(64, 1)
void lsap_kernel(const float* __restrict__ y_true, const float* __restrict__ y_pred,
                 float* __restrict__ batch_sums, float* __restrict__ out, int use_atomic) {
    __shared__ float dist[N * N];            // 64 KB; columns ca/cb read only by owner lane (JV part)
    __shared__ float ytl[N * DIM];           // 32 KB
    __shared__ float v_lds[N];               // price mirror for row scans
    __shared__ unsigned bid[N];              // auction bid box: (monokey(newv)&~127) | row
    __shared__ int rowfree[N];               // auction row freeness
    __shared__ int unlist[N + ARR_CAP + 8];  // free-row queue

    const int b = blockIdx.x;
    const int lane = threadIdx.x;
    const int ca = lane, cb = lane + 64;
    const int ja = lane + 1, jb = lane + 65;

    // ---- stage y_true[b] into LDS ----
    {
        const float4* yt4 = (const float4*)(y_true + (size_t)b * N * DIM);
        float4* ytl4 = (float4*)ytl;
        for (int k = lane; k < N * DIM / 4; k += 64) ytl4[k] = yt4[k];
    }

    // ---- y_pred rows ca, cb into registers ----
    float ypa[DIM], ypb[DIM];
    {
        const float4* pa4 = (const float4*)(y_pred + (size_t)b * N * DIM + (size_t)ca * DIM);
        const float4* pb4 = (const float4*)(y_pred + (size_t)b * N * DIM + (size_t)cb * DIM);
        #pragma unroll
        for (int k = 0; k < DIM / 4; ++k) {
            float4 v4 = pa4[k];
            ypa[4*k+0]=v4.x; ypa[4*k+1]=v4.y; ypa[4*k+2]=v4.z; ypa[4*k+3]=v4.w;
            float4 w4 = pb4[k];
            ypb[4*k+0]=w4.x; ypb[4*k+1]=w4.y; ypb[4*k+2]=w4.z; ypb[4*k+3]=w4.w;
        }
    }
    __syncthreads();   // ytl visible

    // ---- Phase A: dist columns + column minima (v init) ----
    float va = INFINITY, vb = INFINITY;      // v[ja], v[jb]
    for (int i = 0; i < N; ++i) {
        const float4* yr = (const float4*)(ytl + i * DIM);
        float a0 = 0.f, a1 = 0.f;
        #pragma unroll
        for (int k = 0; k < DIM / 4; ++k) {
            float4 t4 = yr[k];
            float d;
            d = t4.x - ypa[4*k+0]; a0 = fmaf(d, d, a0);
            d = t4.y - ypa[4*k+1]; a0 = fmaf(d, d, a0);
            d = t4.z - ypa[4*k+2]; a0 = fmaf(d, d, a0);
            d = t4.w - ypa[4*k+3]; a0 = fmaf(d, d, a0);
            d = t4.x - ypb[4*k+0]; a1 = fmaf(d, d, a1);
            d = t4.y - ypb[4*k+1]; a1 = fmaf(d, d, a1);
            d = t4.z - ypb[4*k+2]; a1 = fmaf(d, d, a1);
            d = t4.w - ypb[4*k+3]; a1 = fmaf(d, d, a1);
        }
        float d0 = sqrtf(a0), d1 = sqrtf(a1);
        dist[i * N + ca] = d0;
        dist[i * N + cb] = d1;
        va = fminf(va, d0);
        vb = fminf(vb, d1);
    }

    // ---- Auction warm-start (capped Jacobi rounds; only v survives) ----
    {
        int ow_a = -1, ow_b = -1;            // auction column owners (0-based rows; -1 free)
        rowfree[lane] = 1; rowfree[lane + 64] = 1;
        for (int rd = 0; rd < AUCTION_ROUNDS; ++rd) {
            float eps = (rd < 8) ? 0.5f : 0.08f;
            v_lds[ca] = va; v_lds[cb] = vb;
            bid[ca] = 0xFFFFFFFFu; bid[cb] = 0xFFFFFFFFu;
            __syncthreads();                 // v/bid/rowfree visible
            int f0 = rowfree[lane], f1 = rowfree[lane + 64];
            int f = __popcll(__ballot(f0)) + __popcll(__ballot(f1));
            if (f <= 4) break;               // uniform
            if (f0) {                        // row `lane` bids
                const float* dr = dist + lane * N;
                float m1 = INFINITY, m2 = INFINITY; int j1 = 0;
                #pragma unroll 4
                for (int t = 0; t < N; ++t) {
                    int j = (t + lane) & (N - 1);
                    float c = dr[j] - v_lds[j];
                    float mx = fmaxf(m1, c);
                    m2 = fminf(m2, mx);
                    if (c < m1) { m1 = c; j1 = j; }
                }
                float newv = v_lds[j1] - (m2 - m1) - eps;
                atomicMin(&bid[j1], (monokey(newv) & ~127u) | (unsigned)lane);
            }
            if (f1) {                        // row `lane+64` bids
                const float* dr = dist + (lane + 64) * N;
                float m1 = INFINITY, m2 = INFINITY; int j1 = 0;
                #pragma unroll 4
                for (int t = 0; t < N; ++t) {
                    int j = (t + lane) & (N - 1);
                    float c = dr[j] - v_lds[j];
                    float mx = fmaxf(m1, c);
                    m2 = fminf(m2, mx);
                    if (c < m1) { m1 = c; j1 = j; }
                }
                float newv = v_lds[j1] - (m2 - m1) - eps;
                atomicMin(&bid[j1], (monokey(newv) & ~127u) | (unsigned)(lane + 64));
            }
            __syncthreads();                 // bids visible
            unsigned w0 = bid[ca];
            if (w0 != 0xFFFFFFFFu) {
                int wr = (int)(w0 & 127u);
                if (ow_a >= 0) rowfree[ow_a] = 1;
                rowfree[wr] = 0;
                ow_a = wr;
                va = monoval(w0 & ~127u);
            }
            unsigned w1 = bid[cb];
            if (w1 != 0xFFFFFFFFu) {
                int wr = (int)(w1 & 127u);
                if (ow_b >= 0) rowfree[ow_b] = 1;
                rowfree[wr] = 0;
                ow_b = wr;
                vb = monoval(w1 & ~127u);
            }
            // rowfree writes become visible at next round's barrier
        }
    }

    // ---- Phase B: exact parallel row minima vs final v; serial greedy (no transfers) ----
    v_lds[ca] = va; v_lds[cb] = vb;
    __syncthreads();
    float m1a = INFINITY, m1b = INFINITY;
    int j1a = 0, j1b = 0;
    {
        const float* dra = dist + lane * N;
        const float* drb = dist + (lane + 64) * N;
        #pragma unroll 4
        for (int t = 0; t < N; ++t) {
            int j = (t + lane) & (N - 1);
            float vj = v_lds[j];
            float c0 = dra[j] - vj;
            float c1 = drb[j] - vj;
            if (c0 < m1a) { m1a = c0; j1a = j; }
            if (c1 < m1b) { m1b = c1; j1b = j; }
        }
    }
    float ura = m1a, urb = m1b;              // u_row (exact rowmin -> feasible duals)

    int   pa = 0, pb = 0;                    // JV column state: assigned row (1-based; 0=free)
    float upa = 0.f, upb = 0.f;              // u[p[j]]
    int   waya = 0, wayb = 0;

    int nun = 0;
    for (int r = 0; r < N; ++r) {
        int w = r & 63, hi = r >> 6;
        int j1 = rl_i(hi ? j1b : j1a, w);    // 0-based tight column of row r
        float u1 = rl_f(hi ? m1b : m1a, w);
        int cw = j1 & 63, cs = j1 >> 6;
        int pj = rl_i(cs ? pb : pa, cw);
        if (pj == 0) {
            if (lane == cw) {
                if (cs) { pb = r + 1; upb = u1; }
                else    { pa = r + 1; upa = u1; }
            }
        } else {
            unlist[nun] = r;
            ++nun;
        }
    }

    // ---- Augmenting row reduction (LAPJV), R7 order; displaced rows speculatively prefetched ----
    int qk = 0, nf = nun;
    {
        int ops = 0;
        int icur = -1;
        float d0c = 0.f, d1c = 0.f;
        int qi = -1; float qd0 = 0.f, qd1 = 0.f;
        if (nun > 0) {
            icur = rfl(unlist[0]); qk = 1;
            d0c = dist[icur * N + ca]; d1c = dist[icur * N + cb];
            if (qk < nf) { qi = rfl(unlist[qk]); qd0 = dist[qi * N + ca]; qd1 = dist[qi * N + cb]; }
        }
        while (icur >= 0 && ops < ARR_CAP) {
            ++ops;
            float c0 = d0c - va, c1 = d1c - vb;
            unsigned k0 = (monokey(c0) & ~0x7Fu) | (unsigned)lane;
            unsigned k1 = (monokey(c1) & ~0x7Fu) | 64u | (unsigned)lane;
            unsigned ks = umin_(k0, k1), kb2 = umax_(k0, k1);
            wave_kmin2(ks, kb2, lane);
            int s1 = rfl((int)ks);
            int s2 = rfl((int)kb2);
            int w1 = s1 & 63, cb1 = (s1 >> 6) & 1;
            int w2 = s2 & 63, cb2 = (s2 >> 6) & 1;
            int pj1 = rl_i(cb1 ? pb : pa, w1);
            int pj2 = rl_i(cb2 ? pb : pa, w2);
            float sa0 = 0.f, sa1 = 0.f, sb0 = 0.f, sb1 = 0.f;
            if (pj1) { sa0 = dist[(pj1 - 1) * N + ca]; sa1 = dist[(pj1 - 1) * N + cb]; }
            if (pj2) { sb0 = dist[(pj2 - 1) * N + ca]; sb1 = dist[(pj2 - 1) * N + cb]; }
            float u1 = rl_f(cb1 ? c1 : c0, w1);
            float u2 = rl_f(cb2 ? c1 : c0, w2);
            int j1 = 1 + w1 + (cb1 << 6);
            int j2 = 1 + w2 + (cb2 << 6);
            bool transfer = (u1 < u2);
            int jt, it0;
            if (transfer) {
                float dd = u2 - u1;
                if (ja == j1) va -= dd;
                if (jb == j1) vb -= dd;
                jt = j1; it0 = pj1;
            } else if (pj1 > 0) { jt = j2; it0 = pj2; }
            else { jt = j1; it0 = 0; }

            if (ja == jt) { pa = icur + 1; upa = u2; }
            if (jb == jt) { pb = icur + 1; upb = u2; }
            if ((icur & 63) == lane) { if (icur < 64) ura = u2; else urb = u2; }

            if (transfer && it0 > 0) {
                icur = it0 - 1; d0c = sa0; d1c = sa1;
            } else {
                if (!transfer && pj1 > 0) { unlist[nf] = it0 - 1; ++nf; }
                if (qk < nf) {
                    if (qi < 0) { icur = it0 - 1; d0c = sb0; d1c = sb1; }
                    else        { icur = qi;      d0c = qd0; d1c = qd1; }
                    ++qk;
                    if (qk < nf) {
                        qi = rfl(unlist[qk]);
                        qd0 = dist[qi * N + ca]; qd1 = dist[qi * N + cb];
                    } else qi = -1;
                } else icur = -1;
            }
        }
        if (icur >= 0) { --qk; unlist[qk] = icur; }
    }

    // ---- Dijkstra augmenting phases for remaining free rows (R7) ----
    for (int t = qk; t < nf; ++t) {
        int r = rfl(unlist[t]);
        float d0 = dist[r * N + ca], d1 = dist[r * N + cb];
        float u_i = rl_f((r >= 64) ? urb : ura, r & 63);
        float mina = INFINITY, minb = INFINITY;
        int useda = 0, usedb = 0;
        waya = 0; wayb = 0;
        float uacca = 0.f, uaccb = 0.f;
        float u_acc_i = u_i;
        float u0c = u_i;
        int j0 = 0;

        for (int it = 0; it < 2 * N; ++it) {
            if (ja == j0) useda = 1;
            if (jb == j0) usedb = 1;
            if (!useda) { float cur = d0 - u0c - va; if (cur < mina) { mina = cur; waya = j0; } }
            if (!usedb) { float cur = d1 - u0c - vb; if (cur < minb) { minb = cur; wayb = j0; } }

            float fa_ = useda ? INFINITY : mina;
            float fb_ = usedb ? INFINITY : minb;
            unsigned kA = (monokey(fa_) & 0xFFFF8000u) | ((unsigned)pa << 7) | (unsigned)lane;
            unsigned kB = (monokey(fb_) & 0xFFFF8000u) | ((unsigned)pb << 7) | 64u | (unsigned)lane;
            unsigned kk = wave_kmin(umin_(kA, kB));
            int s = rfl((int)kk);
            int i1 = (s >> 7) & 0xFF;

            float nd0 = 0.f, nd1 = 0.f;
            if (i1) { nd0 = dist[(i1 - 1) * N + ca]; nd1 = dist[(i1 - 1) * N + cb]; }

            int w = s & 63, cbw = (s >> 6) & 1;
            float delta = rl_f(cbw ? fb_ : fa_, w);
            float u1v = rl_f(cbw ? upb : upa, w);

            if (useda) { va -= delta; uacca += delta; } else { mina -= delta; }
            if (usedb) { vb -= delta; uaccb += delta; } else { minb -= delta; }
            u_acc_i += delta;

            j0 = 1 + w + (cbw << 6);
            if (i1 == 0) break;
            u0c = u1v; d0 = nd0; d1 = nd1;
        }

        if (useda) upa += uacca;
        if (usedb) upb += uaccb;

        int jj = j0;
        for (int hop = 0; hop < N + 1; ++hop) {
            int wj = (jj - 1) & 63;
            int sbj = (jj > 64) ? 1 : 0;
            int jp = rl_i(sbj ? wayb : waya, wj);
            int np; float nu;
            if (jp == 0) { np = r + 1; nu = u_acc_i; }
            else {
                int wp = (jp - 1) & 63;
                int sbp = (jp > 64) ? 1 : 0;
                np = rl_i(sbp ? pb : pa, wp);
                nu = rl_f(sbp ? upb : upa, wp);
            }
            if (ja == jj) { pa = np; upa = nu; }
            if (jb == jj) { pb = np; upb = nu; }
            if (jp == 0) break;
            jj = jp;
        }
    }

    // ---- matched sum ----
    float s = dist[(pa - 1) * N + ca] + dist[(pb - 1) * N + cb];
    #pragma unroll
    for (int m = 1; m < 64; m <<= 1) s += __shfl_xor(s, m);
    if (lane == 0) {
        if (use_atomic) atomicAdd(out, s * (1.0f / (float)BATCH));
        else batch_sums[b] = s;
    }
}

__global__ __launch_bounds__(64)
void reduce_kernel(const float* __restrict__ bs, float* __restrict__ out) {
    int tid = threadIdx.x;
    float v = bs[tid];
    #pragma unroll
    for (int m = 1; m < 64; m <<= 1) v += __shfl_xor(v, m);
    if (tid == 0) out[0] = v * (1.0f / (float)BATCH);
}

extern "C" void kernel_launch(void* const* d_in, const int* in_sizes, int n_in,
                              void* d_out, int out_size, void* d_ws, size_t ws_size,
                              hipStream_t stream) {
    const float* y_true = (const float*)d_in[0];
    const float* y_pred = (const float*)d_in[1];
    float* out = (float*)d_out;

    if (ws_size >= BATCH * sizeof(float)) {
        float* bs = (float*)d_ws;
        lsap_kernel<<<BATCH, 64, 0, stream>>>(y_true, y_pred, bs, out, 0);
        reduce_kernel<<<1, 64, 0, stream>>>(bs, out);
    } else {
        hipMemsetAsync(d_out, 0, sizeof(float), stream);
        lsap_kernel<<<BATCH, 64, 0, stream>>>(y_true, y_pred, nullptr, out, 1);
    }
}

// Round 9
// 646.983 us; speedup vs baseline: 1.0706x; 1.0706x over previous
//
#include <hip/hip_runtime.h>
#include <math.h>
#include <stdint.h>

#define BATCH 64
#define N 128
#define DIM 64
#define ARR_CAP 640

typedef unsigned uint32x2_t __attribute__((ext_vector_type(2)));

// branchless monotone float->uint (order-preserving incl. +-inf)
__device__ __forceinline__ unsigned monokey(float x) {
    unsigned b = __float_as_uint(x);
    return b ^ (unsigned)(((int)b >> 31) | (int)0x80000000u);
}

__device__ __forceinline__ unsigned umin_(unsigned a, unsigned b) { return a < b ? a : b; }
__device__ __forceinline__ unsigned umax_(unsigned a, unsigned b) { return a > b ? a : b; }
__device__ __forceinline__ int rfl(int v) { return __builtin_amdgcn_readfirstlane(v); }
__device__ __forceinline__ int rl_i(int v, int l) { return __builtin_amdgcn_readlane(v, l); }
__device__ __forceinline__ float rl_f(float v, int l) {
    return __int_as_float(__builtin_amdgcn_readlane(__float_as_int(v), l));
}

#define DPP_ROR(x, n) __builtin_amdgcn_update_dpp((int)(x), (int)(x), 0x120 + (n), 0xF, 0xF, false)

// full-wave min of packed keys; every lane gets the result. VALU-only.
__device__ __forceinline__ unsigned wave_kmin(unsigned k) {
    unsigned a = (unsigned)DPP_ROR(k, 1);
    unsigned b = (unsigned)DPP_ROR(k, 2);
    k = umin_(k, umin_(a, b));            // 0..2
    a = (unsigned)DPP_ROR(k, 3);
    b = (unsigned)DPP_ROR(k, 6);
    k = umin_(k, umin_(a, b));            // 0..8
    a = (unsigned)DPP_ROR(k, 9);
    k = umin_(k, a);                      // 0..15 (wrap overlap OK for min)
#if __has_builtin(__builtin_amdgcn_permlane16_swap)
    { uint32x2_t r = __builtin_amdgcn_permlane16_swap(k, k, false, false); k = umin_(r[0], r[1]); }
#else
    k = umin_(k, (unsigned)__shfl_xor((int)k, 16));
#endif
#if __has_builtin(__builtin_amdgcn_permlane32_swap)
    { uint32x2_t r = __builtin_amdgcn_permlane32_swap(k, k, false, false); k = umin_(r[0], r[1]); }
#else
    k = umin_(k, (unsigned)__shfl_xor((int)k, 32));
#endif
    return k;
}

// two smallest keys across the wave (disjoint-window rotate-reduce). ks<=kb kept.
__device__ __forceinline__ void wave_kmin2(unsigned& ks, unsigned& kb, int lane) {
    unsigned ps, pb;
#define KM2_COMBINE { unsigned ns = umin_(ks, ps); kb = umin_(umin_(kb, pb), umax_(ks, ps)); ks = ns; }
    ps = (unsigned)DPP_ROR(ks, 1); pb = (unsigned)DPP_ROR(kb, 1); KM2_COMBINE;
    ps = (unsigned)DPP_ROR(ks, 2); pb = (unsigned)DPP_ROR(kb, 2); KM2_COMBINE;
    ps = (unsigned)DPP_ROR(ks, 4); pb = (unsigned)DPP_ROR(kb, 4); KM2_COMBINE;
    ps = (unsigned)DPP_ROR(ks, 8); pb = (unsigned)DPP_ROR(kb, 8); KM2_COMBINE;
#if __has_builtin(__builtin_amdgcn_permlane16_swap)
    {
        uint32x2_t rs = __builtin_amdgcn_permlane16_swap(ks, ks, false, false);
        uint32x2_t rb = __builtin_amdgcn_permlane16_swap(kb, kb, false, false);
        ps = (lane & 16) ? rs[0] : rs[1]; pb = (lane & 16) ? rb[0] : rb[1];
    }
    KM2_COMBINE;
#else
    ps = (unsigned)__shfl_xor((int)ks, 16); pb = (unsigned)__shfl_xor((int)kb, 16); KM2_COMBINE;
#endif
#if __has_builtin(__builtin_amdgcn_permlane32_swap)
    {
        uint32x2_t rs = __builtin_amdgcn_permlane32_swap(ks, ks, false, false);
        uint32x2_t rb = __builtin_amdgcn_permlane32_swap(kb, kb, false, false);
        ps = (lane & 32) ? rs[0] : rs[1]; pb = (lane & 32) ? rb[0] : rb[1];
    }
    KM2_COMBINE;
#else
    ps = (unsigned)__shfl_xor((int)ks, 32); pb = (unsigned)__shfl_xor((int)kb, 32); KM2_COMBINE;
#endif
#undef KM2_COMBINE
}

// One block = one batch, 64 threads (1 wave). Lane owns 1-based columns ja=lane+1, jb=lane+65.
// Pipeline: col-min duals -> greedy(+reduction transfer) -> ARR (R7-proven) ->
// multi-source shortest augmenting path for the remaining free rows.
__global__ __launch_bounds__(64, 1)
void lsap_kernel(const float* __restrict__ y_true, const float* __restrict__ y_pred,
                 float* __restrict__ batch_sums, float* __restrict__ out, int use_atomic) {
    __shared__ float dist[N * N];            // 64 KB; columns ca/cb read only by owner lane
    __shared__ float ytl[N * DIM];           // 32 KB
    __shared__ int unlist[N + ARR_CAP + 8];  // free-row queue (phase B / ARR)
    __shared__ int flags[N];                 // assigned-row flags (post-ARR)

    const int b = blockIdx.x;
    const int lane = threadIdx.x;
    const int ca = lane, cb = lane + 64;
    const int ja = lane + 1, jb = lane + 65;

    // ---- stage y_true[b] into LDS ----
    {
        const float4* yt4 = (const float4*)(y_true + (size_t)b * N * DIM);
        float4* ytl4 = (float4*)ytl;
        for (int k = lane; k < N * DIM / 4; k += 64) ytl4[k] = yt4[k];
    }

    // ---- y_pred rows ca, cb into registers ----
    float ypa[DIM], ypb[DIM];
    {
        const float4* pa4 = (const float4*)(y_pred + (size_t)b * N * DIM + (size_t)ca * DIM);
        const float4* pb4 = (const float4*)(y_pred + (size_t)b * N * DIM + (size_t)cb * DIM);
        #pragma unroll
        for (int k = 0; k < DIM / 4; ++k) {
            float4 v4 = pa4[k];
            ypa[4*k+0]=v4.x; ypa[4*k+1]=v4.y; ypa[4*k+2]=v4.z; ypa[4*k+3]=v4.w;
            float4 w4 = pb4[k];
            ypb[4*k+0]=w4.x; ypb[4*k+1]=w4.y; ypb[4*k+2]=w4.z; ypb[4*k+3]=w4.w;
        }
    }
    __syncthreads();   // ytl visible

    // ---- Phase A: dist columns + column minima (v init) ----
    float va = INFINITY, vb = INFINITY;      // v[ja], v[jb]
    for (int i = 0; i < N; ++i) {
        const float4* yr = (const float4*)(ytl + i * DIM);
        float a0 = 0.f, a1 = 0.f;
        #pragma unroll
        for (int k = 0; k < DIM / 4; ++k) {
            float4 t4 = yr[k];
            float d;
            d = t4.x - ypa[4*k+0]; a0 = fmaf(d, d, a0);
            d = t4.y - ypa[4*k+1]; a0 = fmaf(d, d, a0);
            d = t4.z - ypa[4*k+2]; a0 = fmaf(d, d, a0);
            d = t4.w - ypa[4*k+3]; a0 = fmaf(d, d, a0);
            d = t4.x - ypb[4*k+0]; a1 = fmaf(d, d, a1);
            d = t4.y - ypb[4*k+1]; a1 = fmaf(d, d, a1);
            d = t4.z - ypb[4*k+2]; a1 = fmaf(d, d, a1);
            d = t4.w - ypb[4*k+3]; a1 = fmaf(d, d, a1);
        }
        float d0 = sqrtf(a0), d1 = sqrtf(a1);
        dist[i * N + ca] = d0;
        dist[i * N + cb] = d1;
        va = fminf(va, d0);
        vb = fminf(vb, d1);
    }

    // Column state in registers.
    int   pa = 0, pb = 0;          // assigned row (1-based; 0=free)
    float upa = 0.f, upb = 0.f;    // u[p[j]]
    float ura = 0.f, urb = 0.f;    // u_row for rows lane / lane+64 (free rows only)

    // ---- Phase B: row minima (kmin2) + greedy assignment with reduction transfer ----
    int nun = 0;
    float pd0 = dist[ca], pd1 = dist[cb];
    for (int r = 0; r < N; ++r) {
        float c0 = pd0 - va, c1 = pd1 - vb;
        if (r + 1 < N) { pd0 = dist[(r+1) * N + ca]; pd1 = dist[(r+1) * N + cb]; }
        unsigned k0 = (monokey(c0) & ~0x7Fu) | (unsigned)lane;
        unsigned k1 = (monokey(c1) & ~0x7Fu) | 64u | (unsigned)lane;
        unsigned ks = umin_(k0, k1), kb2 = umax_(k0, k1);
        wave_kmin2(ks, kb2, lane);
        int s1 = rfl((int)ks);
        int s2 = rfl((int)kb2);
        int w1 = s1 & 63, cb1 = (s1 >> 6) & 1;
        float u1 = rl_f(cb1 ? c1 : c0, w1);
        float u2 = rl_f(((s2 >> 6) & 1) ? c1 : c0, s2 & 63);
        int j1 = 1 + w1 + (cb1 << 6);
        int pj1 = rl_i(cb1 ? pb : pa, w1);
        if (pj1 == 0) {
            float dd = u2 - u1;              // reduction transfer
            if (ja == j1) { pa = r + 1; upa = u2; va -= dd; }
            if (jb == j1) { pb = r + 1; upb = u2; vb -= dd; }
            if ((r & 63) == lane) { if (r < 64) ura = u2; else urb = u2; }
        } else {
            unlist[nun] = r;
            ++nun;
            if ((r & 63) == lane) { if (r < 64) ura = u1; else urb = u1; }
        }
    }

    // ---- Augmenting row reduction (LAPJV), R7 order; displaced rows speculatively prefetched ----
    {
        int qk = 0, nf = nun, ops = 0;
        int icur = -1;
        float d0c = 0.f, d1c = 0.f;
        int qi = -1; float qd0 = 0.f, qd1 = 0.f;
        if (nun > 0) {
            icur = rfl(unlist[0]); qk = 1;
            d0c = dist[icur * N + ca]; d1c = dist[icur * N + cb];
            if (qk < nf) { qi = rfl(unlist[qk]); qd0 = dist[qi * N + ca]; qd1 = dist[qi * N + cb]; }
        }
        while (icur >= 0 && ops < ARR_CAP) {
            ++ops;
            float c0 = d0c - va, c1 = d1c - vb;
            unsigned k0 = (monokey(c0) & ~0x7Fu) | (unsigned)lane;
            unsigned k1 = (monokey(c1) & ~0x7Fu) | 64u | (unsigned)lane;
            unsigned ks = umin_(k0, k1), kb2 = umax_(k0, k1);
            wave_kmin2(ks, kb2, lane);
            int s1 = rfl((int)ks);
            int s2 = rfl((int)kb2);
            int w1 = s1 & 63, cb1 = (s1 >> 6) & 1;
            int w2 = s2 & 63, cb2 = (s2 >> 6) & 1;
            int pj1 = rl_i(cb1 ? pb : pa, w1);
            int pj2 = rl_i(cb2 ? pb : pa, w2);
            float sa0 = 0.f, sa1 = 0.f, sb0 = 0.f, sb1 = 0.f;
            if (pj1) { sa0 = dist[(pj1 - 1) * N + ca]; sa1 = dist[(pj1 - 1) * N + cb]; }
            if (pj2) { sb0 = dist[(pj2 - 1) * N + ca]; sb1 = dist[(pj2 - 1) * N + cb]; }
            float u1 = rl_f(cb1 ? c1 : c0, w1);
            float u2 = rl_f(cb2 ? c1 : c0, w2);
            int j1 = 1 + w1 + (cb1 << 6);
            int j2 = 1 + w2 + (cb2 << 6);
            bool transfer = (u1 < u2);
            int jt, it0;
            if (transfer) {
                float dd = u2 - u1;
                if (ja == j1) va -= dd;
                if (jb == j1) vb -= dd;
                jt = j1; it0 = pj1;
            } else if (pj1 > 0) { jt = j2; it0 = pj2; }
            else { jt = j1; it0 = 0; }

            if (ja == jt) { pa = icur + 1; upa = u2; }
            if (jb == jt) { pb = icur + 1; upb = u2; }
            if ((icur & 63) == lane) { if (icur < 64) ura = u2; else urb = u2; }

            if (transfer && it0 > 0) {
                icur = it0 - 1; d0c = sa0; d1c = sa1;
            } else {
                if (!transfer && pj1 > 0) { unlist[nf] = it0 - 1; ++nf; }
                if (qk < nf) {
                    if (qi < 0) { icur = it0 - 1; d0c = sb0; d1c = sb1; }
                    else        { icur = qi;      d0c = qd0; d1c = qd1; }
                    ++qk;
                    if (qk < nf) {
                        qi = rfl(unlist[qk]);
                        qd0 = dist[qi * N + ca]; qd1 = dist[qi * N + cb];
                    } else qi = -1;
                } else icur = -1;
            }
        }
        // any unprocessed rows remain free; flags pass below catches them
    }

    // ---- build free-row flags from column ownership ----
    flags[lane] = 0; flags[lane + 64] = 0;
    __syncthreads();
    if (pa) flags[pa - 1] = 1;
    if (pb) flags[pb - 1] = 1;
    __syncthreads();
    int fra = flags[lane] ^ 1;        // row `lane` free?
    int frb = flags[lane + 64] ^ 1;   // row `lane+64` free?

    // ---- multi-source shortest augmenting path phases ----
    for (int phase = 0; phase < N; ++phase) {
        unsigned long long m0 = __ballot(fra), m1 = __ballot(frb);
        if (!(m0 | m1)) break;

        // init: minv[own cols] = min over free rows r of (dist[r][c] - u[r]) - v[c]
        float mina = INFINITY, minb = INFINITY;
        int waya = 0, wayb = 0;       // <0 => -(src_row+1); >0 => 1-based predecessor col
        unsigned long long mm = m0;
        while (mm) {
            int r = (int)(__ffsll(mm) - 1); mm &= mm - 1;
            float ur = rl_f(ura, r);
            float q0 = dist[r * N + ca] - ur;
            float q1 = dist[r * N + cb] - ur;
            if (q0 < mina) { mina = q0; waya = -(r + 1); }
            if (q1 < minb) { minb = q1; wayb = -(r + 1); }
        }
        mm = m1;
        while (mm) {
            int rr = (int)(__ffsll(mm) - 1); mm &= mm - 1;
            float ur = rl_f(urb, rr);
            int r = rr + 64;
            float q0 = dist[r * N + ca] - ur;
            float q1 = dist[r * N + cb] - ur;
            if (q0 < mina) { mina = q0; waya = -(r + 1); }
            if (q1 < minb) { minb = q1; wayb = -(r + 1); }
        }
        mina -= va; minb -= vb;

        int useda = 0, usedb = 0;
        float uacca = 0.f, uaccb = 0.f;
        float dsum = 0.f;
        int j0 = 0;

        for (int it = 0; it < 2 * N; ++it) {
            float fa_ = useda ? INFINITY : mina;
            float fb_ = usedb ? INFINITY : minb;
            // key: [31:15] value, [14:7] p (0=free col), [6] colbit, [5:0] lane
            unsigned kA = (monokey(fa_) & 0xFFFF8000u) | ((unsigned)pa << 7) | (unsigned)lane;
            unsigned kB = (monokey(fb_) & 0xFFFF8000u) | ((unsigned)pb << 7) | 64u | (unsigned)lane;
            unsigned kk = wave_kmin(umin_(kA, kB));
            int s = rfl((int)kk);
            int i1 = (s >> 7) & 0xFF;                 // owner of settled col (0 => free col)
            int w = s & 63, cbw = (s >> 6) & 1;
            int jn = 1 + w + (cbw << 6);              // settled column (1-based)
            // issue relax-row loads ASAP (harmless if i1==0)
            int ipf = (i1 ? i1 : 1) - 1;
            float d0 = dist[ipf * N + ca], d1 = dist[ipf * N + cb];
            float delta = rl_f(cbw ? fb_ : fa_, w);   // exact
            float u0c = rl_f(cbw ? upb : upa, w);     // pre-phase u of owner

            // dual bookkeeping with OLD used flags (e-maxx order), then mark jn used
            if (useda) { va -= delta; uacca += delta; } else { mina -= delta; }
            if (usedb) { vb -= delta; uaccb += delta; } else { minb -= delta; }
            dsum += delta;
            if (ja == jn) useda = 1;
            if (jb == jn) usedb = 1;
            j0 = jn;
            if (i1 == 0) break;

            // relax with row i1 (pre-phase duals for unused cols)
            if (!useda) { float cur = d0 - u0c - va; if (cur < mina) { mina = cur; waya = jn; } }
            if (!usedb) { float cur = d1 - u0c - vb; if (cur < minb) { minb = cur; wayb = jn; } }
        }

        // deferred dual updates for used columns
        if (useda) upa += uacca;
        if (usedb) upb += uaccb;
        // all free rows' u += dsum (incl. the row about to be assigned -> tight entry edge)
        if (fra) ura += dsum;
        if (frb) urb += dsum;

        // augment: register readlane chase; way<0 terminates with the source row
        int jj = j0;
        for (int hop = 0; hop <= N; ++hop) {
            int wj = (jj - 1) & 63;
            int sbj = (jj > 64) ? 1 : 0;
            int jp = rl_i(sbj ? wayb : waya, wj);
            int np; float nu;
            if (jp < 0) {
                int rs = -jp - 1;
                np = rs + 1;
                nu = rl_f((rs >= 64) ? urb : ura, rs & 63);
                if ((rs & 63) == lane) { if (rs < 64) fra = 0; else frb = 0; }
            } else {
                int wp = (jp - 1) & 63;
                int sbp = (jp > 64) ? 1 : 0;
                np = rl_i(sbp ? pb : pa, wp);
                nu = rl_f(sbp ? upb : upa, wp);
            }
            if (ja == jj) { pa = np; upa = nu; }
            if (jb == jj) { pb = np; upb = nu; }
            if (jp < 0) break;
            jj = jp;
        }
    }

    // ---- matched sum ----
    float s = dist[(pa - 1) * N + ca] + dist[(pb - 1) * N + cb];
    #pragma unroll
    for (int m = 1; m < 64; m <<= 1) s += __shfl_xor(s, m);
    if (lane == 0) {
        if (use_atomic) atomicAdd(out, s * (1.0f / (float)BATCH));
        else batch_sums[b] = s;
    }
}

__global__ __launch_bounds__(64)
void reduce_kernel(const float* __restrict__ bs, float* __restrict__ out) {
    int tid = threadIdx.x;
    float v = bs[tid];
    #pragma unroll
    for (int m = 1; m < 64; m <<= 1) v += __shfl_xor(v, m);
    if (tid == 0) out[0] = v * (1.0f / (float)BATCH);
}

extern "C" void kernel_launch(void* const* d_in, const int* in_sizes, int n_in,
                              void* d_out, int out_size, void* d_ws, size_t ws_size,
                              hipStream_t stream) {
    const float* y_true = (const float*)d_in[0];
    const float* y_pred = (const float*)d_in[1];
    float* out = (float*)d_out;

    if (ws_size >= BATCH * sizeof(float)) {
        float* bs = (float*)d_ws;
        lsap_kernel<<<BATCH, 64, 0, stream>>>(y_true, y_pred, bs, out, 0);
        reduce_kernel<<<1, 64, 0, stream>>>(bs, out);
    } else {
        hipMemsetAsync(d_out, 0, sizeof(float), stream);
        lsap_kernel<<<BATCH, 64, 0, stream>>>(y_true, y_pred, nullptr, out, 1);
    }
}

// Round 10
// 592.957 us; speedup vs baseline: 1.1681x; 1.0911x over previous
//
#include <hip/hip_runtime.h>
#include <math.h>
#include <stdint.h>

#define BATCH 64
#define N 128
#define DIM 64
#define ARR_CAP 640

typedef unsigned uint32x2_t __attribute__((ext_vector_type(2)));

// branchless monotone float->uint (order-preserving incl. +-inf)
__device__ __forceinline__ unsigned monokey(float x) {
    unsigned b = __float_as_uint(x);
    return b ^ (unsigned)(((int)b >> 31) | (int)0x80000000u);
}

__device__ __forceinline__ unsigned umin_(unsigned a, unsigned b) { return a < b ? a : b; }
__device__ __forceinline__ unsigned umax_(unsigned a, unsigned b) { return a > b ? a : b; }
__device__ __forceinline__ int rfl(int v) { return __builtin_amdgcn_readfirstlane(v); }
__device__ __forceinline__ int rl_i(int v, int l) { return __builtin_amdgcn_readlane(v, l); }
__device__ __forceinline__ float rl_f(float v, int l) {
    return __int_as_float(__builtin_amdgcn_readlane(__float_as_int(v), l));
}

#define DPP_ROR(x, n) __builtin_amdgcn_update_dpp((int)(x), (int)(x), 0x120 + (n), 0xF, 0xF, false)

// full-wave min of packed keys; every lane gets the result. VALU-only.
__device__ __forceinline__ unsigned wave_kmin(unsigned k) {
    unsigned a = (unsigned)DPP_ROR(k, 1);
    unsigned b = (unsigned)DPP_ROR(k, 2);
    k = umin_(k, umin_(a, b));            // 0..2
    a = (unsigned)DPP_ROR(k, 3);
    b = (unsigned)DPP_ROR(k, 6);
    k = umin_(k, umin_(a, b));            // 0..8
    a = (unsigned)DPP_ROR(k, 9);
    k = umin_(k, a);                      // 0..15 (wrap overlap OK for min)
#if __has_builtin(__builtin_amdgcn_permlane16_swap)
    { uint32x2_t r = __builtin_amdgcn_permlane16_swap(k, k, false, false); k = umin_(r[0], r[1]); }
#else
    k = umin_(k, (unsigned)__shfl_xor((int)k, 16));
#endif
#if __has_builtin(__builtin_amdgcn_permlane32_swap)
    { uint32x2_t r = __builtin_amdgcn_permlane32_swap(k, k, false, false); k = umin_(r[0], r[1]); }
#else
    k = umin_(k, (unsigned)__shfl_xor((int)k, 32));
#endif
    return k;
}

// two smallest keys across the wave (disjoint-window rotate-reduce). ks<=kb kept.
__device__ __forceinline__ void wave_kmin2(unsigned& ks, unsigned& kb, int lane) {
    unsigned ps, pb;
#define KM2_COMBINE { unsigned ns = umin_(ks, ps); kb = umin_(umin_(kb, pb), umax_(ks, ps)); ks = ns; }
    ps = (unsigned)DPP_ROR(ks, 1); pb = (unsigned)DPP_ROR(kb, 1); KM2_COMBINE;
    ps = (unsigned)DPP_ROR(ks, 2); pb = (unsigned)DPP_ROR(kb, 2); KM2_COMBINE;
    ps = (unsigned)DPP_ROR(ks, 4); pb = (unsigned)DPP_ROR(kb, 4); KM2_COMBINE;
    ps = (unsigned)DPP_ROR(ks, 8); pb = (unsigned)DPP_ROR(kb, 8); KM2_COMBINE;
#if __has_builtin(__builtin_amdgcn_permlane16_swap)
    {
        uint32x2_t rs = __builtin_amdgcn_permlane16_swap(ks, ks, false, false);
        uint32x2_t rb = __builtin_amdgcn_permlane16_swap(kb, kb, false, false);
        ps = (lane & 16) ? rs[0] : rs[1]; pb = (lane & 16) ? rb[0] : rb[1];
    }
    KM2_COMBINE;
#else
    ps = (unsigned)__shfl_xor((int)ks, 16); pb = (unsigned)__shfl_xor((int)kb, 16); KM2_COMBINE;
#endif
#if __has_builtin(__builtin_amdgcn_permlane32_swap)
    {
        uint32x2_t rs = __builtin_amdgcn_permlane32_swap(ks, ks, false, false);
        uint32x2_t rb = __builtin_amdgcn_permlane32_swap(kb, kb, false, false);
        ps = (lane & 32) ? rs[0] : rs[1]; pb = (lane & 32) ? rb[0] : rb[1];
    }
    KM2_COMBINE;
#else
    ps = (unsigned)__shfl_xor((int)ks, 32); pb = (unsigned)__shfl_xor((int)kb, 32); KM2_COMBINE;
#endif
#undef KM2_COMBINE
}

// One block = one batch, 64 threads (1 wave). Lane owns 1-based columns ja=lane+1, jb=lane+65.
// Same algorithm as the 592us R7 kernel; Dijkstra settle loop rewritten in absolute-potential
// space (per-iteration dual updates replaced by settle-time stamps + closed-form finalize).
__global__ __launch_bounds__(64, 1)
void lsap_kernel(const float* __restrict__ y_true, const float* __restrict__ y_pred,
                 float* __restrict__ batch_sums, float* __restrict__ out, int use_atomic) {
    __shared__ float dist[N * N];            // 64 KB; columns ca/cb read only by owner lane
    __shared__ float ytl[N * DIM];           // 32 KB
    __shared__ int unlist[N + ARR_CAP + 8];  // free-row queue

    const int b = blockIdx.x;
    const int lane = threadIdx.x;
    const int ca = lane, cb = lane + 64;
    const int ja = lane + 1, jb = lane + 65;

    // ---- stage y_true[b] into LDS ----
    {
        const float4* yt4 = (const float4*)(y_true + (size_t)b * N * DIM);
        float4* ytl4 = (float4*)ytl;
        for (int k = lane; k < N * DIM / 4; k += 64) ytl4[k] = yt4[k];
    }

    // ---- y_pred rows ca, cb into registers ----
    float ypa[DIM], ypb[DIM];
    {
        const float4* pa4 = (const float4*)(y_pred + (size_t)b * N * DIM + (size_t)ca * DIM);
        const float4* pb4 = (const float4*)(y_pred + (size_t)b * N * DIM + (size_t)cb * DIM);
        #pragma unroll
        for (int k = 0; k < DIM / 4; ++k) {
            float4 v4 = pa4[k];
            ypa[4*k+0]=v4.x; ypa[4*k+1]=v4.y; ypa[4*k+2]=v4.z; ypa[4*k+3]=v4.w;
            float4 w4 = pb4[k];
            ypb[4*k+0]=w4.x; ypb[4*k+1]=w4.y; ypb[4*k+2]=w4.z; ypb[4*k+3]=w4.w;
        }
    }
    __syncthreads();   // ytl visible

    // ---- Phase A: dist columns + column minima (v init) ----
    float va = INFINITY, vb = INFINITY;      // v[ja], v[jb]
    for (int i = 0; i < N; ++i) {
        const float4* yr = (const float4*)(ytl + i * DIM);
        float a0 = 0.f, a1 = 0.f;
        #pragma unroll
        for (int k = 0; k < DIM / 4; ++k) {
            float4 t4 = yr[k];
            float d;
            d = t4.x - ypa[4*k+0]; a0 = fmaf(d, d, a0);
            d = t4.y - ypa[4*k+1]; a0 = fmaf(d, d, a0);
            d = t4.z - ypa[4*k+2]; a0 = fmaf(d, d, a0);
            d = t4.w - ypa[4*k+3]; a0 = fmaf(d, d, a0);
            d = t4.x - ypb[4*k+0]; a1 = fmaf(d, d, a1);
            d = t4.y - ypb[4*k+1]; a1 = fmaf(d, d, a1);
            d = t4.z - ypb[4*k+2]; a1 = fmaf(d, d, a1);
            d = t4.w - ypb[4*k+3]; a1 = fmaf(d, d, a1);
        }
        float d0 = sqrtf(a0), d1 = sqrtf(a1);
        dist[i * N + ca] = d0;
        dist[i * N + cb] = d1;
        va = fminf(va, d0);
        vb = fminf(vb, d1);
    }

    // Column state in registers.
    int   pa = 0, pb = 0;          // assigned row (1-based; 0=free)
    float upa = 0.f, upb = 0.f;    // u[p[j]]
    float ura = 0.f, urb = 0.f;    // u_row for rows lane / lane+64

    // ---- Phase B: row minima (kmin2) + greedy assignment with reduction transfer ----
    int nun = 0;
    float pd0 = dist[ca], pd1 = dist[cb];
    for (int r = 0; r < N; ++r) {
        float c0 = pd0 - va, c1 = pd1 - vb;
        if (r + 1 < N) { pd0 = dist[(r+1) * N + ca]; pd1 = dist[(r+1) * N + cb]; }
        unsigned k0 = (monokey(c0) & ~0x7Fu) | (unsigned)lane;
        unsigned k1 = (monokey(c1) & ~0x7Fu) | 64u | (unsigned)lane;
        unsigned ks = umin_(k0, k1), kb2 = umax_(k0, k1);
        wave_kmin2(ks, kb2, lane);
        int s1 = rfl((int)ks);
        int s2 = rfl((int)kb2);
        int w1 = s1 & 63, cb1 = (s1 >> 6) & 1;
        float u1 = rl_f(cb1 ? c1 : c0, w1);
        float u2 = rl_f(((s2 >> 6) & 1) ? c1 : c0, s2 & 63);
        int j1 = 1 + w1 + (cb1 << 6);
        int pj1 = rl_i(cb1 ? pb : pa, w1);
        if (pj1 == 0) {
            float dd = u2 - u1;              // reduction transfer
            if (ja == j1) { pa = r + 1; upa = u2; va -= dd; }
            if (jb == j1) { pb = r + 1; upb = u2; vb -= dd; }
            if ((r & 63) == lane) { if (r < 64) ura = u2; else urb = u2; }
        } else {
            unlist[nun] = r;
            ++nun;
            if ((r & 63) == lane) { if (r < 64) ura = u1; else urb = u1; }
        }
    }

    // ---- Augmenting row reduction (LAPJV), R7 order; displaced rows speculatively prefetched ----
    int qk = 0, nf = nun;
    {
        int ops = 0;
        int icur = -1;
        float d0c = 0.f, d1c = 0.f;
        int qi = -1; float qd0 = 0.f, qd1 = 0.f;
        if (nun > 0) {
            icur = rfl(unlist[0]); qk = 1;
            d0c = dist[icur * N + ca]; d1c = dist[icur * N + cb];
            if (qk < nf) { qi = rfl(unlist[qk]); qd0 = dist[qi * N + ca]; qd1 = dist[qi * N + cb]; }
        }
        while (icur >= 0 && ops < ARR_CAP) {
            ++ops;
            float c0 = d0c - va, c1 = d1c - vb;
            unsigned k0 = (monokey(c0) & ~0x7Fu) | (unsigned)lane;
            unsigned k1 = (monokey(c1) & ~0x7Fu) | 64u | (unsigned)lane;
            unsigned ks = umin_(k0, k1), kb2 = umax_(k0, k1);
            wave_kmin2(ks, kb2, lane);
            int s1 = rfl((int)ks);
            int s2 = rfl((int)kb2);
            int w1 = s1 & 63, cb1 = (s1 >> 6) & 1;
            int w2 = s2 & 63, cb2 = (s2 >> 6) & 1;
            int pj1 = rl_i(cb1 ? pb : pa, w1);
            int pj2 = rl_i(cb2 ? pb : pa, w2);
            float sa0 = 0.f, sa1 = 0.f, sb0 = 0.f, sb1 = 0.f;
            if (pj1) { sa0 = dist[(pj1 - 1) * N + ca]; sa1 = dist[(pj1 - 1) * N + cb]; }
            if (pj2) { sb0 = dist[(pj2 - 1) * N + ca]; sb1 = dist[(pj2 - 1) * N + cb]; }
            float u1 = rl_f(cb1 ? c1 : c0, w1);
            float u2 = rl_f(cb2 ? c1 : c0, w2);
            int j1 = 1 + w1 + (cb1 << 6);
            int j2 = 1 + w2 + (cb2 << 6);
            bool transfer = (u1 < u2);
            int jt, it0;
            if (transfer) {
                float dd = u2 - u1;
                if (ja == j1) va -= dd;
                if (jb == j1) vb -= dd;
                jt = j1; it0 = pj1;
            } else if (pj1 > 0) { jt = j2; it0 = pj2; }
            else { jt = j1; it0 = 0; }

            if (ja == jt) { pa = icur + 1; upa = u2; }
            if (jb == jt) { pb = icur + 1; upb = u2; }
            if ((icur & 63) == lane) { if (icur < 64) ura = u2; else urb = u2; }

            if (transfer && it0 > 0) {
                icur = it0 - 1; d0c = sa0; d1c = sa1;
            } else {
                if (!transfer && pj1 > 0) { unlist[nf] = it0 - 1; ++nf; }
                if (qk < nf) {
                    if (qi < 0) { icur = it0 - 1; d0c = sb0; d1c = sb1; }
                    else        { icur = qi;      d0c = qd0; d1c = qd1; }
                    ++qk;
                    if (qk < nf) {
                        qi = rfl(unlist[qk]);
                        qd0 = dist[qi * N + ca]; qd1 = dist[qi * N + cb];
                    } else qi = -1;
                } else icur = -1;
            }
        }
        if (icur >= 0) { --qk; unlist[qk] = icur; }
    }

    // ---- Dijkstra augmenting phases (absolute-potential space) ----
    for (int t = qk; t < nf; ++t) {
        int r = rfl(unlist[t]);
        float d0s = dist[r * N + ca], d1s = dist[r * N + cb];   // source row
        float u_i = rl_f((r >= 64) ? urb : ura, r & 63);

        const float va0 = va, vb0 = vb;       // pre-search duals (restored at finalize)
        float mina = d0s - u_i - va;          // minv in ABSOLUTE space (dsum-shifted)
        float minb = d1s - u_i - vb;
        int waya = 0, wayb = 0;
        float dsa = -1.0f, dsb = -1.0f;       // settle-time dsum stamps (-1 = not settled)
        const unsigned pka = ((unsigned)pa << 7) | (unsigned)lane;          // hoisted packs
        const unsigned pkb = ((unsigned)pb << 7) | 64u | (unsigned)lane;
        float dsum = 0.f;
        int j0 = 0;

        for (int it = 0; it < 2 * N; ++it) {
            // keys: [31:15] truncated value, [14:7] owner p, [6] colbit, [5:0] lane
            unsigned kA = (monokey(mina) & 0xFFFF8000u) | pka;
            unsigned kB = (monokey(minb) & 0xFFFF8000u) | pkb;
            unsigned kk = wave_kmin(umin_(kA, kB));
            int s = rfl((int)kk);
            int i1 = (s >> 7) & 0xFF;                 // owner of settled col (0 => free col)
            int w = s & 63, cbw = (s >> 6) & 1;

            // issue relax-row LDS loads immediately (SALU-decoded address)
            int ip = (i1 ? i1 - 1 : 0) * N;
            float nd0 = dist[ip + ca], nd1 = dist[ip + cb];

            float mch = cbw ? minb : mina;
            float uch = cbw ? upb : upa;
            float ds_new = rl_f(mch, w);              // exact: dsum_new = winner's abs-minv
            float u0 = rl_f(uch, w);                  // owner's pre-search u

            int jn = 1 + w + (cbw << 6);
            if (ja == jn) { mina = INFINITY; va = -INFINITY; dsa = ds_new; }
            if (jb == jn) { minb = INFINITY; vb = -INFINITY; dsb = ds_new; }
            dsum = ds_new;
            j0 = jn;
            if (i1 == 0) break;

            // relax from row i1 (abs space); settled own col yields +INF via va=-INF
            float tt = dsum - u0;
            float c0 = nd0 + tt - va;
            float c1 = nd1 + tt - vb;
            if (c0 < mina) { mina = c0; waya = jn; }
            if (c1 < minb) { minb = c1; wayb = jn; }
        }

        // ---- closed-form dual finalization ----
        float u_acc_i = u_i + dsum;
        bool sa = (dsa >= 0.f), sb = (dsb >= 0.f);
        va = sa ? (va0 - (dsum - dsa)) : va0;
        vb = sb ? (vb0 - (dsum - dsb)) : vb0;
        if (sa) upa += (dsum - dsa);
        if (sb) upb += (dsum - dsb);

        // ---- augment: register readlane chase (R7 verbatim) ----
        int jj = j0;
        for (int hop = 0; hop < N + 1; ++hop) {
            int wj = (jj - 1) & 63;
            int sbj = (jj > 64) ? 1 : 0;
            int jp = rl_i(sbj ? wayb : waya, wj);
            int np; float nu;
            if (jp == 0) { np = r + 1; nu = u_acc_i; }
            else {
                int wp = (jp - 1) & 63;
                int sbp = (jp > 64) ? 1 : 0;
                np = rl_i(sbp ? pb : pa, wp);
                nu = rl_f(sbp ? upb : upa, wp);
            }
            if (ja == jj) { pa = np; upa = nu; }
            if (jb == jj) { pb = np; upb = nu; }
            if (jp == 0) break;
            jj = jp;
        }
    }

    // ---- matched sum ----
    float s = dist[(pa - 1) * N + ca] + dist[(pb - 1) * N + cb];
    #pragma unroll
    for (int m = 1; m < 64; m <<= 1) s += __shfl_xor(s, m);
    if (lane == 0) {
        if (use_atomic) atomicAdd(out, s * (1.0f / (float)BATCH));
        else batch_sums[b] = s;
    }
}

__global__ __launch_bounds__(64)
void reduce_kernel(const float* __restrict__ bs, float* __restrict__ out) {
    int tid = threadIdx.x;
    float v = bs[tid];
    #pragma unroll
    for (int m = 1; m < 64; m <<= 1) v += __shfl_xor(v, m);
    if (tid == 0) out[0] = v * (1.0f / (float)BATCH);
}

extern "C" void kernel_launch(void* const* d_in, const int* in_sizes, int n_in,
                              void* d_out, int out_size, void* d_ws, size_t ws_size,
                              hipStream_t stream) {
    const float* y_true = (const float*)d_in[0];
    const float* y_pred = (const float*)d_in[1];
    float* out = (float*)d_out;

    if (ws_size >= BATCH * sizeof(float)) {
        float* bs = (float*)d_ws;
        lsap_kernel<<<BATCH, 64, 0, stream>>>(y_true, y_pred, bs, out, 0);
        reduce_kernel<<<1, 64, 0, stream>>>(bs, out);
    } else {
        hipMemsetAsync(d_out, 0, sizeof(float), stream);
        lsap_kernel<<<BATCH, 64, 0, stream>>>(y_true, y_pred, nullptr, out, 1);
    }
}